// Round 16
// baseline (617.406 us; speedup 1.0000x reference)
//
#include <hip/hip_runtime.h>
#include <math.h>

// Problem constants
#define TT   52        // time steps
#define BBAT 4         // batch
#define CCH  9         // input channels
#define HWP  4096      // 64*64 pixels per image
#define FF   64        // features
#define NP   16384     // b*h*w pixels
#define TD   5         // theta dim
#define NCC  6         // tessellation cells
#define TSTRIDE 147456 // b*c*h*w (stride of t in x, floats)

// output offsets (floats)
#define OUT0 0
#define OUT1 (NP*CCH*TT)        // x_shift_pix
#define OUT2 (2*NP*CCH*TT)      // theta_pred
#define OUT3 (OUT2 + NP*TD)     // theta_shift

// workspace offsets (floats)
#define WS_BF    0      // 60 floats: CPAB basis
#define WS_WIMG  1024   // 12*64 int4: w1a/w2a fragment image
#define WS_AIMG  4096   // 8*32*64 int4 = 65536 floats: fc1w A-fragment image
#define WS_XPIX  69632  // NP*CCH*TT floats: x pixel-major [n][c][t] (optional)

typedef __attribute__((ext_vector_type(8)))  short short8v;
typedef __attribute__((ext_vector_type(4)))  float f32x4;
typedef __attribute__((ext_vector_type(4)))  int   int4v;
typedef __attribute__((ext_vector_type(2)))  int   int2v;

// RNE f32->bf16 bits, packed pair (scalar fallback, prep kernels)
__device__ __forceinline__ unsigned bfb(float f) {
    unsigned x = __builtin_bit_cast(unsigned, f);
    return (x + 0x7fffu + ((x >> 16) & 1u)) >> 16;
}
__device__ __forceinline__ unsigned pk2(float a, float b) {
    return bfb(a) | (bfb(b) << 16);
}
// HW packed convert (1 VALU op): D.lo = bf16(a), D.hi = bf16(b)
__device__ __forceinline__ unsigned cvtpk(float a, float b) {
    unsigned r;
    asm("v_cvt_pk_bf16_f32 %0, %1, %2" : "=v"(r) : "v"(a), "v"(b));
    return r;
}
// zP row-XOR helper
__device__ __forceinline__ int nswz(int n) {
    return (((n ^ (n >> 3)) & 1) << 6) | (((n >> 1) & 3) << 4);
}

// ---------------------------------------------------------------------------
// k_pre: merged prep. block 0: basis (wave 0) + conv fragments (wave 1);
// blocks 1..64: fc1w A-fragment image; blocks 65..576: x -> xp transpose
// (32-pixel tiles, all 9 channels staged in LDS [468][33], coalesced writes).
// ---------------------------------------------------------------------------
__global__ __launch_bounds__(256) void k_pre(
    const float* __restrict__ lniw, const float* __restrict__ lnib,
    const float* __restrict__ w1c,  const float* __restrict__ b1c,
    const float* __restrict__ w2c,  const float* __restrict__ fc1w,
    const float* __restrict__ x,
    float* __restrict__ Bout, int4v* __restrict__ wimg,
    int4v* __restrict__ aimg, float* __restrict__ xp, int use_xp)
{
    __shared__ float ld[468 * 33];   // 61.8KB (transpose blocks only)
    int blk = blockIdx.x;
    int tid = threadIdx.x;

    if (blk == 0) {
        if (tid < 64) {
            // ---- basis: np.linalg.svd(L) null-space (dgesdd LQ path) ----
            int k = tid;
            double Acol[7], Vcol[7], Mcol[5];
#pragma unroll
            for (int r = 0; r < 7; r++) { Acol[r] = 0.0; Vcol[r] = 0.0; }
#pragma unroll
            for (int j = 0; j < 5; j++) Mcol[j] = 0.0;
            if (k < 12) {
#pragma unroll
                for (int j = 1; j < 6; j++) {
                    int r = j - 1;
                    double xj = (double)j / 6.0;
                    if (k == 2 * (j - 1))     Acol[r] = xj;
                    if (k == 2 * (j - 1) + 1) Acol[r] = 1.0;
                    if (k == 2 * j)           Acol[r] = -xj;
                    if (k == 2 * j + 1)       Acol[r] = -1.0;
                }
                if (k == 1)  Acol[5] = 1.0;
                if (k == 10) Acol[6] = 1.0;
                if (k == 11) Acol[6] = 1.0;
#pragma unroll
                for (int j = 0; j < 5; j++) Mcol[j] = (k == 7 + j) ? 1.0 : 0.0;
            }
            double tau[7];
#pragma unroll
            for (int i = 0; i < 7; i++) {
                double c = (k > i && k < 12) ? Acol[i] * Acol[i] : 0.0;
#pragma unroll
                for (int off = 1; off < 64; off <<= 1) c += __shfl_xor(c, off, 64);
                double alpha = __shfl(Acol[i], i, 64);
                double t_i, vk;
                if (c == 0.0) {
                    t_i = 0.0;
                    vk = (k == i) ? 1.0 : 0.0;
                } else {
                    double nrm  = sqrt(alpha * alpha + c);
                    double beta = (alpha >= 0.0) ? -nrm : nrm;  // Fortran SIGN
                    t_i = (beta - alpha) / beta;
                    double inv = 1.0 / (alpha - beta);
                    vk = (k == i) ? 1.0 : ((k > i && k < 12) ? Acol[i] * inv : 0.0);
                }
                tau[i]  = t_i;
                Vcol[i] = vk;
#pragma unroll
                for (int r = 0; r < 7; r++) {
                    if (r > i) {
                        double w = Acol[r] * vk;
#pragma unroll
                        for (int off = 1; off < 64; off <<= 1) w += __shfl_xor(w, off, 64);
                        Acol[r] -= t_i * w * vk;
                    }
                }
            }
#pragma unroll
            for (int i = 6; i >= 0; i--) {
#pragma unroll
                for (int j = 0; j < 5; j++) {
                    double w = Mcol[j] * Vcol[i];
#pragma unroll
                    for (int off = 1; off < 64; off <<= 1) w += __shfl_xor(w, off, 64);
                    Mcol[j] -= tau[i] * w * Vcol[i];
                }
            }
            if (k < 12) {
#pragma unroll
                for (int j = 0; j < 5; j++) Bout[k * 5 + j] = (float)Mcol[j];
            }
        } else if (tid < 128) {
            // ---- conv1/conv2 MFMA A-fragments -> wimg ----
            int lane = tid - 64;
            int pl = lane & 15, h = lane >> 4;
#pragma unroll
            for (int mt = 0; mt < 4; ++mt) {
                int f = mt * 16 + pl;
                float b0f = b1c[f];
#pragma unroll
                for (int c = 0; c < 9; ++c) b0f += lnib[c] * w1c[c * 64 + f];
                float v[8];
#pragma unroll
                for (int i = 0; i < 8; ++i) {
                    int c  = h * 8 + i;
                    int cc = c < 9 ? c : 8;
                    float lv = lniw[cc] * w1c[cc * 64 + f];
                    v[i] = (c < 9) ? lv : ((c == 9) ? b0f : 0.f);
                }
                wimg[mt * 64 + lane] = (int4v){(int)pk2(v[0],v[1]), (int)pk2(v[2],v[3]),
                                               (int)pk2(v[4],v[5]), (int)pk2(v[6],v[7])};
            }
#pragma unroll
            for (int mt2 = 0; mt2 < 4; ++mt2) {
                int g = mt2 * 16 + pl;
#pragma unroll
                for (int ks = 0; ks < 2; ++ks) {
                    float v[8];
#pragma unroll
                    for (int i = 0; i < 8; ++i) v[i] = w2c[(ks * 32 + h * 8 + i) * 64 + g];
                    wimg[(4 + mt2 * 2 + ks) * 64 + lane] =
                        (int4v){(int)pk2(v[0],v[1]), (int)pk2(v[2],v[3]),
                                (int)pk2(v[4],v[5]), (int)pk2(v[6],v[7])};
                }
            }
        }
    } else if (blk <= 64) {
        // ---- fc1w -> bf16 A-fragment image (pad positions zeroed) ----
        int gid  = (blk - 1) * 256 + tid;
        int lane = gid & 63;
        int tc   = gid >> 6;
        int t = tc >> 5, c = tc & 31;
        int bt = t >> 2, tt0 = (t & 3) << 4;
        int m = lane & 15, h = lane >> 4;
        float v[8];
#pragma unroll
        for (int i = 0; i < 8; ++i) {
            int k = c * 32 + h * 8 + i;
            int pos_l = k >> 6, g = k & 63;
            int tt = tt0 + pos_l;
            v[i] = (tt < 52) ? fc1w[(bt * 3328 + g * 52 + tt) * 16 + m] : 0.f;
        }
        aimg[gid] = (int4v){(int)pk2(v[0],v[1]), (int)pk2(v[2],v[3]),
                            (int)pk2(v[4],v[5]), (int)pk2(v[6],v[7])};
    } else if (use_xp) {
        // ---- transpose: 32-pixel tiles, all 9 channels, coalesced writes ----
        int b2 = blk - 65;               // 0..511
        int b  = b2 >> 7, pt = b2 & 127;
        int p0 = pt * 32;
        for (int idx = tid; idx < 9 * 52 * 32; idx += 256) {
            int c  = idx / 1664;         // 52*32
            int r  = idx - c * 1664;
            int t  = r >> 5, pp = r & 31;
            ld[(c * 52 + t) * 33 + pp] = x[((t * BBAT + b) * CCH + c) * HWP + p0 + pp];
        }
        __syncthreads();
        int wv_ = tid >> 6, ln = tid & 63;
        for (int pn = wv_; pn < 32; pn += 4) {
            float* dst = xp + (size_t)(b * HWP + p0 + pn) * 468;
#pragma unroll
            for (int e0 = 0; e0 < 468; e0 += 64) {
                int e = e0 + ln;
                if (e < 468) dst[e] = ld[e * 33 + pn];
            }
        }
    }
}

// ---------------------------------------------------------------------------
// k_cpab: CPAB ODE via closed-form segment jumping, CANCELLATION-FREE form.
// Round-15 bug: landing via fixed point p = -B/hA subtracts huge numbers
// when |hA| is tiny (|p| ~ 1e3+) -> 1e-4 absolute error per iteration ->
// absmax 0.70. Fix: never form p. Identities (vh = hA*x + B = one-step
// displacement, exactly computed):
//   x_k = x + vh * expm1f(k*log1pf(hA)) / hA          (stable at any hA)
//   r-1 = (cb-x)*hA/vh                                 (small, no cancel)
//   kf  = log1pf(r-1) / log1pf(hA)
// Cell-5 upper boundary: v(1)=0 makes u=(r-1) == -1 exactly -> unreachable
// branch (converge to knot, never cross) -> k=rem, same stable landing.
// Any fp edge (landing on knot, cb-x<0 by rounding) gives kf<=0 -> k=1 =
// one exact Euler step; guaranteed progress. |hA|<1e-12 -> linear path.
// ---------------------------------------------------------------------------
__global__ __launch_bounds__(256) void k_cpab(
    const float* __restrict__ x, const float* __restrict__ xp, int use_xp,
    const float* __restrict__ theta, const float* __restrict__ Bf,
    float scale, float* __restrict__ out,
    float* __restrict__ outts, int do_ts)
{
    __shared__ float As[256 * 13];   // hA per cell
    __shared__ float Bs[256 * 13];   // B  per cell
    int tid = threadIdx.x;
    int gid = blockIdx.x * 256 + tid;
    if (gid >= NP * 13) return;
    if (do_ts && gid < NP * TD) outts[gid] = 0.5f * theta[gid];
    int n  = gid / 13;
    int i0 = gid - n * 13;

    float th[TD];
#pragma unroll
    for (int j = 0; j < TD; j++) th[j] = scale * theta[n * TD + j];

#pragma unroll
    for (int i = 0; i < NCC; i++) {
        float aa = 0.f, bb = 0.f;
#pragma unroll
        for (int j = 0; j < TD; j++) {
            aa += th[j] * Bf[(2 * i) * TD + j];
            bb += th[j] * Bf[(2 * i + 1) * TD + j];
        }
        As[tid * 13 + i] = 0.01f * aa;   // hA
        Bs[tid * 13 + i] = 0.01f * bb;   // B
    }
    const float* Ab = &As[tid * 13];
    const float* Bb = &Bs[tid * 13];

    float xcs[4];
    for (int c = 0; c < 4; ++c) {
        float xv = (float)(i0 + 13 * c) / 51.0f;
        int rem = 100;
        while (rem > 0) {
            int i = (int)(xv * 6.0f);
            i = i < 5 ? i : 5;
            float hA = Ab[i], B = Bb[i];
            float vh = fmaf(hA, xv, B);           // per-step displacement
            if (vh == 0.0f) break;
            float cb = (vh > 0.0f) ? (float)(i + 1) * (1.0f / 6.0f)
                                   : (float)i * (1.0f / 6.0f);
            float w_ = (cb - xv) / vh;            // linear step-count estimate
            int k;
            float xn;
            if (fabsf(hA) < 1e-12f) {
                float kf = fminf(fmaxf(w_, 0.0f), 200.0f);
                k = (int)ceilf(kf);
                if (k < 1) k = 1;
                if (k > rem) k = rem;
                xn = fmaf((float)k, vh, xv);
            } else {
                float lnA = log1pf(hA);
                float u   = w_ * hA;              // = r - 1, cancellation-free
                if (u <= -1.0f) {
                    k = rem;                      // fixed point before boundary
                } else {
                    float kf = log1pf(u) / lnA;
                    kf = fminf(fmaxf(kf, 0.0f), 200.0f);
                    k = (int)ceilf(kf);
                    if (k < 1) k = 1;
                    if (k > rem) k = rem;
                }
                xn = fmaf(expm1f((float)k * lnA) / hA, vh, xv);
            }
            xv = __builtin_amdgcn_fmed3f(xn, 0.0f, 1.0f);
            rem -= k;
        }
        xcs[c] = xv;
    }

#pragma unroll
    for (int c2 = 0; c2 < 4; ++c2) {
        float xc = xcs[c2];
        int   tt = i0 + 13 * c2;
        float pos = xc * 51.0f;
        int x0 = (int)floorf(pos);
        if (x0 < 0) x0 = 0;
        if (x0 > 50) x0 = 50;
        float w = pos - (float)x0;
        if (use_xp) {
            const float* row = xp + (size_t)n * (CCH * TT);
#pragma unroll
            for (int ch = 0; ch < CCH; ++ch) {
                float d0 = row[ch * TT + x0];
                float d1 = row[ch * TT + x0 + 1];
                out[n * (CCH * TT) + ch * TT + tt] = d0 * (1.0f - w) + d1 * w;
            }
        } else {
            int bb_ = n >> 12, p = n & 4095;
            int base0 = ((x0 * BBAT + bb_) * CCH) * HWP + p;
#pragma unroll
            for (int ch = 0; ch < CCH; ++ch) {
                float d0 = x[base0 + ch * HWP];
                float d1 = x[base0 + ch * HWP + TSTRIDE];
                out[n * (CCH * TT) + ch * TT + tt] = d0 * (1.0f - w) + d1 * w;
            }
        }
    }
}

// ---------------------------------------------------------------------------
// k_loc (full-MFMA, 16 px / 8 waves / 512 threads). Unchanged from round 13
// (T14 async-stage split, double-buffered zcs/zchs, 2 barriers/tile,
// dred aliased into zP, launch_bounds(512,2) — CUDA-style blocks/CU arg).
// ---------------------------------------------------------------------------
__global__ __launch_bounds__(512, 2) void k_loc(
    const float* __restrict__ x,     // [52,4,9,64,64]
    const float* __restrict__ xs,    // x_shift_pix [N,9,52]
    const int4v* __restrict__ wimg,  // conv fragment image
    const int4v* __restrict__ aimg,  // fc1w A-fragment image
    const float* __restrict__ b2c,
    const float* __restrict__ lncw,  const float* __restrict__ lncb,
    const float* __restrict__ fc1b,
    const float* __restrict__ fc2w,  const float* __restrict__ fc2b,
    float* __restrict__ outtheta)    // [N,5]
{
    __shared__ int4v          zcs[2][256];     // 8KB  zc lo-8, double-buffered
    __shared__ unsigned       zchs[2][256];    // 2KB  pk2(c8, bias), dbuf
    __shared__ unsigned short y1b[8][16][64];  // 16KB per-wave y1 tile
    __shared__ unsigned short zP[16][1024];    // 32KB z2 [px][k]; epilogue: dred alias

    int tid    = threadIdx.x;
    int lane   = tid & 63;
    int wv     = tid >> 6;          // 0..7
    int base16 = blockIdx.x * 16;
    int bb_    = base16 >> 12, p0 = base16 & 4095;
    int pl     = lane & 15;
    int h      = lane >> 4;

    auto ln9_load = [&](int bt_, int tt_, int px_, float* dst) {
        if (tt_ < 52) {
            if (bt_ == 0) {
                int base = ((tt_ * BBAT + bb_) * CCH) * HWP + p0 + px_;
#pragma unroll
                for (int c = 0; c < 9; ++c) dst[c] = x[base + c * HWP];
            } else {
                int base = (base16 + px_) * (CCH * TT) + tt_;
#pragma unroll
                for (int c = 0; c < 9; ++c) dst[c] = xs[base + c * TT];
            }
        }
    };
    auto ln9_store = [&](int buf_, int tt_, int px_, int q_, const float* xin_) {
        float zc[9], bias;
        if (tt_ < 52) {
            float s1 = 0.f, s2 = 0.f;
#pragma unroll
            for (int c = 0; c < 9; ++c) { s1 += xin_[c]; s2 += xin_[c] * xin_[c]; }
            float m  = s1 * (1.0f / 9.0f);
            float vv = fmaxf(s2 * (1.0f / 9.0f) - m * m, 0.f);
            float rs = rsqrtf(vv + 1e-5f);
#pragma unroll
            for (int c = 0; c < 9; ++c) zc[c] = (xin_[c] - m) * rs;
            bias = 1.0f;
        } else {
#pragma unroll
            for (int c = 0; c < 9; ++c) zc[c] = 0.f;
            bias = 0.f;
        }
        zcs[buf_][px_ * 16 + (q_ ^ (px_ & 7))] =
            (int4v){(int)cvtpk(zc[0], zc[1]), (int)cvtpk(zc[2], zc[3]),
                    (int)cvtpk(zc[4], zc[5]), (int)cvtpk(zc[6], zc[7])};
        zchs[buf_][px_ * 16 + q_] = cvtpk(zc[8], bias);
    };

    // ---- fragments (coalesced b128 from wimg) ----
    short8v w1a[4], w2a[4][2];
#pragma unroll
    for (int mt = 0; mt < 4; ++mt)
        w1a[mt] = __builtin_bit_cast(short8v, wimg[mt * 64 + lane]);
#pragma unroll
    for (int mt2 = 0; mt2 < 4; ++mt2)
#pragma unroll
        for (int ks = 0; ks < 2; ++ks)
            w2a[mt2][ks] = __builtin_bit_cast(short8v, wimg[(4 + mt2 * 2 + ks) * 64 + lane]);

    f32x4 b2v[4], lw4[4], lb4[4];
#pragma unroll
    for (int mt2 = 0; mt2 < 4; ++mt2) {
        b2v[mt2] = *(const f32x4*)(b2c  + mt2 * 16 + h * 4);
        lw4[mt2] = *(const f32x4*)(lncw + mt2 * 16 + h * 4);
        lb4[mt2] = *(const f32x4*)(lncb + mt2 * 16 + h * 4);
    }

    f32x4 dacc = (f32x4){0.f, 0.f, 0.f, 0.f};

    // ---- prologue: stage tile 0 (bt=0) ----
    if (tid < 256) {
        float xcur[9];
        int px = tid & 15, q = tid >> 4;
        ln9_load(0, q, px, xcur);
        ln9_store(0, q, px, q, xcur);
    }
    __syncthreads();

    for (int t = 0; t < 8; ++t) {
        int buf = t & 1;

        // ---- (A) prefetch tile t+1 into registers ----
        float xnx[9];
        int btn = (t + 1) >> 2, tt0n = ((t + 1) & 3) << 4;
        int pxn = 0, qn = 0;
        if (tid < 256 && t < 7) {
            if (btn == 0) { pxn = tid & 15; qn = tid >> 4; }
            else          { pxn = tid >> 4; qn = tid & 15; }
            ln9_load(btn, tt0n + qn, pxn, xnx);
        }

        // ---- (B) conv: 2 pixels per wave (reads zcs[buf]) ----
        int sw = (pl & 7) << 3;
#pragma unroll
        for (int sub = 0; sub < 2; ++sub) {
            int px = wv * 2 + sub;
            int nswp = nswz(px);

            short8v b1f;
            if (h == 1) {
                unsigned zv = zchs[buf][px * 16 + pl];
                b1f = __builtin_bit_cast(short8v, (int4v){(int)zv, 0, 0, 0});
            } else {
                b1f = __builtin_bit_cast(short8v, zcs[buf][px * 16 + (pl ^ (px & 7))]);
            }

#pragma unroll
            for (int mt = 0; mt < 4; ++mt) {
                f32x4 c1 = __builtin_amdgcn_mfma_f32_16x16x32_bf16(
                    w1a[mt], b1f, (f32x4){0.f, 0.f, 0.f, 0.f}, 0, 0, 0);
                float v0 = fmaxf(c1[0], 0.f), v1 = fmaxf(c1[1], 0.f);
                float v2 = fmaxf(c1[2], 0.f), v3 = fmaxf(c1[3], 0.f);
                int f0 = (mt * 16 + h * 4) ^ sw;
                *(int2v*)&y1b[wv][pl][f0] = (int2v){(int)cvtpk(v0, v1), (int)cvtpk(v2, v3)};
            }

            short8v b2f0 = *(const short8v*)&y1b[wv][pl][(h * 8) ^ sw];
            short8v b2f1 = *(const short8v*)&y1b[wv][pl][(32 + h * 8) ^ sw];
            float y2[4][4];
#pragma unroll
            for (int mt2 = 0; mt2 < 4; ++mt2) {
                f32x4 c2 = b2v[mt2];
                c2 = __builtin_amdgcn_mfma_f32_16x16x32_bf16(w2a[mt2][0], b2f0, c2, 0, 0, 0);
                c2 = __builtin_amdgcn_mfma_f32_16x16x32_bf16(w2a[mt2][1], b2f1, c2, 0, 0, 0);
                y2[mt2][0] = fmaxf(c2[0], 0.f);
                y2[mt2][1] = fmaxf(c2[1], 0.f);
                y2[mt2][2] = fmaxf(c2[2], 0.f);
                y2[mt2][3] = fmaxf(c2[3], 0.f);
            }

            // LN64
            float s = 0.f, q = 0.f;
#pragma unroll
            for (int mt2 = 0; mt2 < 4; ++mt2)
#pragma unroll
                for (int r = 0; r < 4; ++r) { s += y2[mt2][r]; q = fmaf(y2[mt2][r], y2[mt2][r], q); }
            s += __shfl_xor(s, 16, 64); s += __shfl_xor(s, 32, 64);
            q += __shfl_xor(q, 16, 64); q += __shfl_xor(q, 32, 64);
            float m2  = s * (1.0f / 64.0f);
            float v2_ = fmaxf(q * (1.0f / 64.0f) - m2 * m2, 0.f);
            float rs2 = rsqrtf(v2_ + 1e-5f);

            // z2 (pad A-columns in aimg are zero; no mask needed)
#pragma unroll
            for (int mt2 = 0; mt2 < 4; ++mt2)
#pragma unroll
                for (int r = 0; r < 4; ++r)
                    y2[mt2][r] = fmaf((y2[mt2][r] - m2) * rs2, lw4[mt2][r], lb4[mt2][r]);

            // z2 pairs -> zP (swizzled)
#pragma unroll
            for (int mt2 = 0; mt2 < 4; ++mt2)
#pragma unroll
                for (int rp = 0; rp < 2; ++rp) {
                    int g0 = mt2 * 16 + h * 4 + rp * 2;
                    int k2 = pl * 128 + g0 * 2;
                    int byte = (px << 11) + ((k2 ^ (((k2 >> 7) & 7) << 4)) ^ nswp);
                    *(unsigned*)((char*)zP + byte) = cvtpk(y2[mt2][rp * 2], y2[mt2][rp * 2 + 1]);
                }
        }
        __syncthreads();   // (C) zP visible to fc1

        // ---- (D) fc1 MFMA: wave covers chunks wv*4..wv*4+3 ----
        const int4v* abase = aimg + (t * 32 + wv * 4) * 64 + lane;
        int nswr = nswz(pl);
#pragma unroll
        for (int cc = 0; cc < 4; ++cc) {
            int c = wv * 4 + cc;
            short8v afrag = __builtin_bit_cast(short8v, abase[cc * 64]);
            int k2 = c * 64 + h * 16;
            int byte = (pl << 11) + ((k2 ^ (((k2 >> 7) & 7) << 4)) ^ nswr);
            short8v bfrag = *(const short8v*)((const char*)zP + byte);
            dacc = __builtin_amdgcn_mfma_f32_16x16x32_bf16(afrag, bfrag, dacc, 0, 0, 0);
        }

        // ---- (E) LN9(t+1) from prefetched regs -> zcs[buf^1] ----
        if (tid < 256 && t < 7)
            ln9_store(buf ^ 1, tt0n + qn, pxn, qn, xnx);

        __syncthreads();   // (F) zP free for next conv; zcs[buf^1] ready
    }

    // ---- epilogue: cross-wave reduce (dred aliased into zP) + fc2 + tanh ----
    float* dred = (float*)zP;                     // [8][16][16] floats = 8KB
    *(f32x4*)&dred[(wv * 16 + pl) * 16 + h * 4] = dacc;
    __syncthreads();
    if (tid < 256) {
        int n4 = tid >> 4, j = tid & 15;
        float hj = 0.f;
#pragma unroll
        for (int w = 0; w < 8; ++w) hj += dred[(w * 16 + n4) * 16 + j];
        hj = fmaxf(hj + fc1b[j], 0.f);
        float th[5];
#pragma unroll
        for (int d = 0; d < 5; ++d) {
            float sd = hj * fc2w[j * 5 + d];
            sd += __shfl_xor(sd, 1, 64); sd += __shfl_xor(sd, 2, 64);
            sd += __shfl_xor(sd, 4, 64); sd += __shfl_xor(sd, 8, 64);
            th[d] = sd;
        }
        if (j < 5) outtheta[(base16 + n4) * TD + j] = tanhf(th[j] + fc2b[j]);
    }
}

// ---------------------------------------------------------------------------
extern "C" void kernel_launch(void* const* d_in, const int* in_sizes, int n_in,
                              void* d_out, int out_size, void* d_ws, size_t ws_size,
                              hipStream_t stream) {
    const float* x     = (const float*)d_in[0];
    const float* thraw = (const float*)d_in[1];
    const float* lniw  = (const float*)d_in[2];
    const float* lnib  = (const float*)d_in[3];
    const float* w1c   = (const float*)d_in[4];
    const float* b1c   = (const float*)d_in[5];
    const float* w2c   = (const float*)d_in[6];
    const float* b2c   = (const float*)d_in[7];
    const float* lncw  = (const float*)d_in[8];
    const float* lncb  = (const float*)d_in[9];
    const float* fc1w  = (const float*)d_in[10];
    const float* fc1b  = (const float*)d_in[11];
    const float* fc2w  = (const float*)d_in[12];
    const float* fc2b  = (const float*)d_in[13];
    float* out  = (float*)d_out;
    float* ws   = (float*)d_ws;
    float* Bf   = ws + WS_BF;
    int4v* wimg = (int4v*)(ws + WS_WIMG);
    int4v* aimg = (int4v*)(ws + WS_AIMG);
    float* xp   = ws + WS_XPIX;
    int use_xp  = (ws_size >= (size_t)(WS_XPIX + NP * CCH * TT) * 4) ? 1 : 0;
    int npre    = use_xp ? (65 + 512) : 65;

    hipLaunchKernelGGL(k_pre, dim3(npre), dim3(256), 0, stream,
                       lniw, lnib, w1c, b1c, w2c, fc1w, x, Bf, wimg, aimg, xp, use_xp);
    hipLaunchKernelGGL(k_cpab, dim3((NP * 13) / 256), dim3(256), 0, stream,
                       x, xp, use_xp, thraw, Bf, 0.5f, out + OUT1, out + OUT3, 1);
    hipLaunchKernelGGL(k_loc, dim3(NP / 16), dim3(512), 0, stream,
                       x, out + OUT1, wimg, aimg, b2c, lncw, lncb,
                       fc1b, fc2w, fc2b, out + OUT2);
    hipLaunchKernelGGL(k_cpab, dim3((NP * 13) / 256), dim3(256), 0, stream,
                       x, xp, use_xp, out + OUT2, Bf, 1.0f, out + OUT0, out, 0);
}

// Round 17
// 184.067 us; speedup vs baseline: 3.3543x; 3.3543x over previous
//
#include <hip/hip_runtime.h>
#include <math.h>

// Problem constants
#define TT   52        // time steps
#define BBAT 4         // batch
#define CCH  9         // input channels
#define HWP  4096      // 64*64 pixels per image
#define FF   64        // features
#define NP   16384     // b*h*w pixels
#define TD   5         // theta dim
#define NCC  6         // tessellation cells
#define TSTRIDE 147456 // b*c*h*w (stride of t in x, floats)

// output offsets (floats)
#define OUT0 0
#define OUT1 (NP*CCH*TT)        // x_shift_pix
#define OUT2 (2*NP*CCH*TT)      // theta_pred
#define OUT3 (OUT2 + NP*TD)     // theta_shift

// workspace offsets (floats)
#define WS_BF    0      // 60 floats: CPAB basis
#define WS_WIMG  1024   // 12*64 int4: w1a/w2a fragment image
#define WS_AIMG  4096   // 8*32*64 int4 = 65536 floats: fc1w A-fragment image
#define WS_XPIX  69632  // NP*CCH*TT floats: x pixel-major [n][c][t] (optional)

typedef __attribute__((ext_vector_type(8)))  short short8v;
typedef __attribute__((ext_vector_type(4)))  float f32x4;
typedef __attribute__((ext_vector_type(4)))  int   int4v;
typedef __attribute__((ext_vector_type(2)))  int   int2v;

// RNE f32->bf16 bits, packed pair (scalar fallback, prep kernels)
__device__ __forceinline__ unsigned bfb(float f) {
    unsigned x = __builtin_bit_cast(unsigned, f);
    return (x + 0x7fffu + ((x >> 16) & 1u)) >> 16;
}
__device__ __forceinline__ unsigned pk2(float a, float b) {
    return bfb(a) | (bfb(b) << 16);
}
// HW packed convert (1 VALU op): D.lo = bf16(a), D.hi = bf16(b)
__device__ __forceinline__ unsigned cvtpk(float a, float b) {
    unsigned r;
    asm("v_cvt_pk_bf16_f32 %0, %1, %2" : "=v"(r) : "v"(a), "v"(b));
    return r;
}
// zP row-XOR helper
__device__ __forceinline__ int nswz(int n) {
    return (((n ^ (n >> 3)) & 1) << 6) | (((n >> 1) & 3) << 4);
}

// ---------------------------------------------------------------------------
// k_pre: merged prep. block 0: basis (wave 0) + conv fragments (wave 1);
// blocks 1..64: fc1w A-fragment image; blocks 65..576: x -> xp transpose
// (32-pixel tiles, all 9 channels staged in LDS [468][33], coalesced writes).
// ---------------------------------------------------------------------------
__global__ __launch_bounds__(256) void k_pre(
    const float* __restrict__ lniw, const float* __restrict__ lnib,
    const float* __restrict__ w1c,  const float* __restrict__ b1c,
    const float* __restrict__ w2c,  const float* __restrict__ fc1w,
    const float* __restrict__ x,
    float* __restrict__ Bout, int4v* __restrict__ wimg,
    int4v* __restrict__ aimg, float* __restrict__ xp, int use_xp)
{
    __shared__ float ld[468 * 33];   // 61.8KB (transpose blocks only)
    int blk = blockIdx.x;
    int tid = threadIdx.x;

    if (blk == 0) {
        if (tid < 64) {
            // ---- basis: np.linalg.svd(L) null-space (dgesdd LQ path) ----
            int k = tid;
            double Acol[7], Vcol[7], Mcol[5];
#pragma unroll
            for (int r = 0; r < 7; r++) { Acol[r] = 0.0; Vcol[r] = 0.0; }
#pragma unroll
            for (int j = 0; j < 5; j++) Mcol[j] = 0.0;
            if (k < 12) {
#pragma unroll
                for (int j = 1; j < 6; j++) {
                    int r = j - 1;
                    double xj = (double)j / 6.0;
                    if (k == 2 * (j - 1))     Acol[r] = xj;
                    if (k == 2 * (j - 1) + 1) Acol[r] = 1.0;
                    if (k == 2 * j)           Acol[r] = -xj;
                    if (k == 2 * j + 1)       Acol[r] = -1.0;
                }
                if (k == 1)  Acol[5] = 1.0;
                if (k == 10) Acol[6] = 1.0;
                if (k == 11) Acol[6] = 1.0;
#pragma unroll
                for (int j = 0; j < 5; j++) Mcol[j] = (k == 7 + j) ? 1.0 : 0.0;
            }
            double tau[7];
#pragma unroll
            for (int i = 0; i < 7; i++) {
                double c = (k > i && k < 12) ? Acol[i] * Acol[i] : 0.0;
#pragma unroll
                for (int off = 1; off < 64; off <<= 1) c += __shfl_xor(c, off, 64);
                double alpha = __shfl(Acol[i], i, 64);
                double t_i, vk;
                if (c == 0.0) {
                    t_i = 0.0;
                    vk = (k == i) ? 1.0 : 0.0;
                } else {
                    double nrm  = sqrt(alpha * alpha + c);
                    double beta = (alpha >= 0.0) ? -nrm : nrm;  // Fortran SIGN
                    t_i = (beta - alpha) / beta;
                    double inv = 1.0 / (alpha - beta);
                    vk = (k == i) ? 1.0 : ((k > i && k < 12) ? Acol[i] * inv : 0.0);
                }
                tau[i]  = t_i;
                Vcol[i] = vk;
#pragma unroll
                for (int r = 0; r < 7; r++) {
                    if (r > i) {
                        double w = Acol[r] * vk;
#pragma unroll
                        for (int off = 1; off < 64; off <<= 1) w += __shfl_xor(w, off, 64);
                        Acol[r] -= t_i * w * vk;
                    }
                }
            }
#pragma unroll
            for (int i = 6; i >= 0; i--) {
#pragma unroll
                for (int j = 0; j < 5; j++) {
                    double w = Mcol[j] * Vcol[i];
#pragma unroll
                    for (int off = 1; off < 64; off <<= 1) w += __shfl_xor(w, off, 64);
                    Mcol[j] -= tau[i] * w * Vcol[i];
                }
            }
            if (k < 12) {
#pragma unroll
                for (int j = 0; j < 5; j++) Bout[k * 5 + j] = (float)Mcol[j];
            }
        } else if (tid < 128) {
            // ---- conv1/conv2 MFMA A-fragments -> wimg ----
            int lane = tid - 64;
            int pl = lane & 15, h = lane >> 4;
#pragma unroll
            for (int mt = 0; mt < 4; ++mt) {
                int f = mt * 16 + pl;
                float b0f = b1c[f];
#pragma unroll
                for (int c = 0; c < 9; ++c) b0f += lnib[c] * w1c[c * 64 + f];
                float v[8];
#pragma unroll
                for (int i = 0; i < 8; ++i) {
                    int c  = h * 8 + i;
                    int cc = c < 9 ? c : 8;
                    float lv = lniw[cc] * w1c[cc * 64 + f];
                    v[i] = (c < 9) ? lv : ((c == 9) ? b0f : 0.f);
                }
                wimg[mt * 64 + lane] = (int4v){(int)pk2(v[0],v[1]), (int)pk2(v[2],v[3]),
                                               (int)pk2(v[4],v[5]), (int)pk2(v[6],v[7])};
            }
#pragma unroll
            for (int mt2 = 0; mt2 < 4; ++mt2) {
                int g = mt2 * 16 + pl;
#pragma unroll
                for (int ks = 0; ks < 2; ++ks) {
                    float v[8];
#pragma unroll
                    for (int i = 0; i < 8; ++i) v[i] = w2c[(ks * 32 + h * 8 + i) * 64 + g];
                    wimg[(4 + mt2 * 2 + ks) * 64 + lane] =
                        (int4v){(int)pk2(v[0],v[1]), (int)pk2(v[2],v[3]),
                                (int)pk2(v[4],v[5]), (int)pk2(v[6],v[7])};
                }
            }
        }
    } else if (blk <= 64) {
        // ---- fc1w -> bf16 A-fragment image (pad positions zeroed) ----
        int gid  = (blk - 1) * 256 + tid;
        int lane = gid & 63;
        int tc   = gid >> 6;
        int t = tc >> 5, c = tc & 31;
        int bt = t >> 2, tt0 = (t & 3) << 4;
        int m = lane & 15, h = lane >> 4;
        float v[8];
#pragma unroll
        for (int i = 0; i < 8; ++i) {
            int k = c * 32 + h * 8 + i;
            int pos_l = k >> 6, g = k & 63;
            int tt = tt0 + pos_l;
            v[i] = (tt < 52) ? fc1w[(bt * 3328 + g * 52 + tt) * 16 + m] : 0.f;
        }
        aimg[gid] = (int4v){(int)pk2(v[0],v[1]), (int)pk2(v[2],v[3]),
                            (int)pk2(v[4],v[5]), (int)pk2(v[6],v[7])};
    } else if (use_xp) {
        // ---- transpose: 32-pixel tiles, all 9 channels, coalesced writes ----
        int b2 = blk - 65;               // 0..511
        int b  = b2 >> 7, pt = b2 & 127;
        int p0 = pt * 32;
        for (int idx = tid; idx < 9 * 52 * 32; idx += 256) {
            int c  = idx / 1664;         // 52*32
            int r  = idx - c * 1664;
            int t  = r >> 5, pp = r & 31;
            ld[(c * 52 + t) * 33 + pp] = x[((t * BBAT + b) * CCH + c) * HWP + p0 + pp];
        }
        __syncthreads();
        int wv_ = tid >> 6, ln = tid & 63;
        for (int pn = wv_; pn < 32; pn += 4) {
            float* dst = xp + (size_t)(b * HWP + p0 + pn) * 468;
#pragma unroll
            for (int e0 = 0; e0 < 468; e0 += 64) {
                int e = e0 + ln;
                if (e < 468) dst[e] = ld[e * 33 + pn];
            }
        }
    }
}

// ---------------------------------------------------------------------------
// k_cpab: ODE + lerp, 4 chains/thread (tt = i0 + 13c), ROUND-14 form
// (uniform 100-step loop — r16's divergent segment-jumping was 10x slower).
// Delta vs r14: A,B merged into one float2 -> 1 ds_read_b64 per chain-step
// instead of 2 ds_read_b32 (halves the DS instruction count, which bound
// r14's k_cpab). Odd float2-stride 13 spreads lanes over all 16 bank pairs.
// ---------------------------------------------------------------------------
__global__ __launch_bounds__(256) void k_cpab(
    const float* __restrict__ x, const float* __restrict__ xp, int use_xp,
    const float* __restrict__ theta, const float* __restrict__ Bf,
    float scale, float* __restrict__ out,
    float* __restrict__ outts, int do_ts)
{
    __shared__ float2 ABs[256 * 13];   // 26.6KB: {A, B} per (thread, cell)
    int tid = threadIdx.x;
    int gid = blockIdx.x * 256 + tid;
    if (gid >= NP * 13) return;
    if (do_ts && gid < NP * TD) outts[gid] = 0.5f * theta[gid];
    int n  = gid / 13;
    int i0 = gid - n * 13;

    float th[TD];
#pragma unroll
    for (int j = 0; j < TD; j++) th[j] = scale * theta[n * TD + j];

#pragma unroll
    for (int i = 0; i < NCC; i++) {
        float aa = 0.f, bb = 0.f;
#pragma unroll
        for (int j = 0; j < TD; j++) {
            aa += th[j] * Bf[(2 * i) * TD + j];
            bb += th[j] * Bf[(2 * i + 1) * TD + j];
        }
        ABs[tid * 13 + i] = make_float2(fmaf(0.01f, aa, 1.0f), 0.01f * bb);
    }
    const float2* ABp = &ABs[tid * 13];

    float xcs[4];
#pragma unroll
    for (int c = 0; c < 4; ++c) xcs[c] = (float)(i0 + 13 * c) / 51.0f;

    for (int s = 0; s < 100; ++s) {
#pragma unroll
        for (int c = 0; c < 4; ++c) {
            int i = (int)(xcs[c] * 6.0f);
            i = i < 5 ? i : 5;
            float2 ab = ABp[i];
            xcs[c] = __builtin_amdgcn_fmed3f(fmaf(ab.x, xcs[c], ab.y), 0.0f, 1.0f);
        }
    }

#pragma unroll
    for (int c2 = 0; c2 < 4; ++c2) {
        float xc = xcs[c2];
        int   tt = i0 + 13 * c2;
        float pos = xc * 51.0f;
        int x0 = (int)floorf(pos);
        if (x0 < 0) x0 = 0;
        if (x0 > 50) x0 = 50;
        float w = pos - (float)x0;
        if (use_xp) {
            const float* row = xp + (size_t)n * (CCH * TT);
#pragma unroll
            for (int ch = 0; ch < CCH; ++ch) {
                float d0 = row[ch * TT + x0];
                float d1 = row[ch * TT + x0 + 1];
                out[n * (CCH * TT) + ch * TT + tt] = d0 * (1.0f - w) + d1 * w;
            }
        } else {
            int bb_ = n >> 12, p = n & 4095;
            int base0 = ((x0 * BBAT + bb_) * CCH) * HWP + p;
#pragma unroll
            for (int ch = 0; ch < CCH; ++ch) {
                float d0 = x[base0 + ch * HWP];
                float d1 = x[base0 + ch * HWP + TSTRIDE];
                out[n * (CCH * TT) + ch * TT + tt] = d0 * (1.0f - w) + d1 * w;
            }
        }
    }
}

// ---------------------------------------------------------------------------
// k_loc (full-MFMA, 16 px / 8 waves / 512 threads). Unchanged from round 13
// (T14 async-stage split, double-buffered zcs/zchs, 2 barriers/tile,
// dred aliased into zP, launch_bounds(512,2) — CUDA-style blocks/CU arg).
// ---------------------------------------------------------------------------
__global__ __launch_bounds__(512, 2) void k_loc(
    const float* __restrict__ x,     // [52,4,9,64,64]
    const float* __restrict__ xs,    // x_shift_pix [N,9,52]
    const int4v* __restrict__ wimg,  // conv fragment image
    const int4v* __restrict__ aimg,  // fc1w A-fragment image
    const float* __restrict__ b2c,
    const float* __restrict__ lncw,  const float* __restrict__ lncb,
    const float* __restrict__ fc1b,
    const float* __restrict__ fc2w,  const float* __restrict__ fc2b,
    float* __restrict__ outtheta)    // [N,5]
{
    __shared__ int4v          zcs[2][256];     // 8KB  zc lo-8, double-buffered
    __shared__ unsigned       zchs[2][256];    // 2KB  pk2(c8, bias), dbuf
    __shared__ unsigned short y1b[8][16][64];  // 16KB per-wave y1 tile
    __shared__ unsigned short zP[16][1024];    // 32KB z2 [px][k]; epilogue: dred alias

    int tid    = threadIdx.x;
    int lane   = tid & 63;
    int wv     = tid >> 6;          // 0..7
    int base16 = blockIdx.x * 16;
    int bb_    = base16 >> 12, p0 = base16 & 4095;
    int pl     = lane & 15;
    int h      = lane >> 4;

    auto ln9_load = [&](int bt_, int tt_, int px_, float* dst) {
        if (tt_ < 52) {
            if (bt_ == 0) {
                int base = ((tt_ * BBAT + bb_) * CCH) * HWP + p0 + px_;
#pragma unroll
                for (int c = 0; c < 9; ++c) dst[c] = x[base + c * HWP];
            } else {
                int base = (base16 + px_) * (CCH * TT) + tt_;
#pragma unroll
                for (int c = 0; c < 9; ++c) dst[c] = xs[base + c * TT];
            }
        }
    };
    auto ln9_store = [&](int buf_, int tt_, int px_, int q_, const float* xin_) {
        float zc[9], bias;
        if (tt_ < 52) {
            float s1 = 0.f, s2 = 0.f;
#pragma unroll
            for (int c = 0; c < 9; ++c) { s1 += xin_[c]; s2 += xin_[c] * xin_[c]; }
            float m  = s1 * (1.0f / 9.0f);
            float vv = fmaxf(s2 * (1.0f / 9.0f) - m * m, 0.f);
            float rs = rsqrtf(vv + 1e-5f);
#pragma unroll
            for (int c = 0; c < 9; ++c) zc[c] = (xin_[c] - m) * rs;
            bias = 1.0f;
        } else {
#pragma unroll
            for (int c = 0; c < 9; ++c) zc[c] = 0.f;
            bias = 0.f;
        }
        zcs[buf_][px_ * 16 + (q_ ^ (px_ & 7))] =
            (int4v){(int)cvtpk(zc[0], zc[1]), (int)cvtpk(zc[2], zc[3]),
                    (int)cvtpk(zc[4], zc[5]), (int)cvtpk(zc[6], zc[7])};
        zchs[buf_][px_ * 16 + q_] = cvtpk(zc[8], bias);
    };

    // ---- fragments (coalesced b128 from wimg) ----
    short8v w1a[4], w2a[4][2];
#pragma unroll
    for (int mt = 0; mt < 4; ++mt)
        w1a[mt] = __builtin_bit_cast(short8v, wimg[mt * 64 + lane]);
#pragma unroll
    for (int mt2 = 0; mt2 < 4; ++mt2)
#pragma unroll
        for (int ks = 0; ks < 2; ++ks)
            w2a[mt2][ks] = __builtin_bit_cast(short8v, wimg[(4 + mt2 * 2 + ks) * 64 + lane]);

    f32x4 b2v[4], lw4[4], lb4[4];
#pragma unroll
    for (int mt2 = 0; mt2 < 4; ++mt2) {
        b2v[mt2] = *(const f32x4*)(b2c  + mt2 * 16 + h * 4);
        lw4[mt2] = *(const f32x4*)(lncw + mt2 * 16 + h * 4);
        lb4[mt2] = *(const f32x4*)(lncb + mt2 * 16 + h * 4);
    }

    f32x4 dacc = (f32x4){0.f, 0.f, 0.f, 0.f};

    // ---- prologue: stage tile 0 (bt=0) ----
    if (tid < 256) {
        float xcur[9];
        int px = tid & 15, q = tid >> 4;
        ln9_load(0, q, px, xcur);
        ln9_store(0, q, px, q, xcur);
    }
    __syncthreads();

    for (int t = 0; t < 8; ++t) {
        int buf = t & 1;

        // ---- (A) prefetch tile t+1 into registers ----
        float xnx[9];
        int btn = (t + 1) >> 2, tt0n = ((t + 1) & 3) << 4;
        int pxn = 0, qn = 0;
        if (tid < 256 && t < 7) {
            if (btn == 0) { pxn = tid & 15; qn = tid >> 4; }
            else          { pxn = tid >> 4; qn = tid & 15; }
            ln9_load(btn, tt0n + qn, pxn, xnx);
        }

        // ---- (B) conv: 2 pixels per wave (reads zcs[buf]) ----
        int sw = (pl & 7) << 3;
#pragma unroll
        for (int sub = 0; sub < 2; ++sub) {
            int px = wv * 2 + sub;
            int nswp = nswz(px);

            short8v b1f;
            if (h == 1) {
                unsigned zv = zchs[buf][px * 16 + pl];
                b1f = __builtin_bit_cast(short8v, (int4v){(int)zv, 0, 0, 0});
            } else {
                b1f = __builtin_bit_cast(short8v, zcs[buf][px * 16 + (pl ^ (px & 7))]);
            }

#pragma unroll
            for (int mt = 0; mt < 4; ++mt) {
                f32x4 c1 = __builtin_amdgcn_mfma_f32_16x16x32_bf16(
                    w1a[mt], b1f, (f32x4){0.f, 0.f, 0.f, 0.f}, 0, 0, 0);
                float v0 = fmaxf(c1[0], 0.f), v1 = fmaxf(c1[1], 0.f);
                float v2 = fmaxf(c1[2], 0.f), v3 = fmaxf(c1[3], 0.f);
                int f0 = (mt * 16 + h * 4) ^ sw;
                *(int2v*)&y1b[wv][pl][f0] = (int2v){(int)cvtpk(v0, v1), (int)cvtpk(v2, v3)};
            }

            short8v b2f0 = *(const short8v*)&y1b[wv][pl][(h * 8) ^ sw];
            short8v b2f1 = *(const short8v*)&y1b[wv][pl][(32 + h * 8) ^ sw];
            float y2[4][4];
#pragma unroll
            for (int mt2 = 0; mt2 < 4; ++mt2) {
                f32x4 c2 = b2v[mt2];
                c2 = __builtin_amdgcn_mfma_f32_16x16x32_bf16(w2a[mt2][0], b2f0, c2, 0, 0, 0);
                c2 = __builtin_amdgcn_mfma_f32_16x16x32_bf16(w2a[mt2][1], b2f1, c2, 0, 0, 0);
                y2[mt2][0] = fmaxf(c2[0], 0.f);
                y2[mt2][1] = fmaxf(c2[1], 0.f);
                y2[mt2][2] = fmaxf(c2[2], 0.f);
                y2[mt2][3] = fmaxf(c2[3], 0.f);
            }

            // LN64
            float s = 0.f, q = 0.f;
#pragma unroll
            for (int mt2 = 0; mt2 < 4; ++mt2)
#pragma unroll
                for (int r = 0; r < 4; ++r) { s += y2[mt2][r]; q = fmaf(y2[mt2][r], y2[mt2][r], q); }
            s += __shfl_xor(s, 16, 64); s += __shfl_xor(s, 32, 64);
            q += __shfl_xor(q, 16, 64); q += __shfl_xor(q, 32, 64);
            float m2  = s * (1.0f / 64.0f);
            float v2_ = fmaxf(q * (1.0f / 64.0f) - m2 * m2, 0.f);
            float rs2 = rsqrtf(v2_ + 1e-5f);

            // z2 (pad A-columns in aimg are zero; no mask needed)
#pragma unroll
            for (int mt2 = 0; mt2 < 4; ++mt2)
#pragma unroll
                for (int r = 0; r < 4; ++r)
                    y2[mt2][r] = fmaf((y2[mt2][r] - m2) * rs2, lw4[mt2][r], lb4[mt2][r]);

            // z2 pairs -> zP (swizzled)
#pragma unroll
            for (int mt2 = 0; mt2 < 4; ++mt2)
#pragma unroll
                for (int rp = 0; rp < 2; ++rp) {
                    int g0 = mt2 * 16 + h * 4 + rp * 2;
                    int k2 = pl * 128 + g0 * 2;
                    int byte = (px << 11) + ((k2 ^ (((k2 >> 7) & 7) << 4)) ^ nswp);
                    *(unsigned*)((char*)zP + byte) = cvtpk(y2[mt2][rp * 2], y2[mt2][rp * 2 + 1]);
                }
        }
        __syncthreads();   // (C) zP visible to fc1

        // ---- (D) fc1 MFMA: wave covers chunks wv*4..wv*4+3 ----
        const int4v* abase = aimg + (t * 32 + wv * 4) * 64 + lane;
        int nswr = nswz(pl);
#pragma unroll
        for (int cc = 0; cc < 4; ++cc) {
            int c = wv * 4 + cc;
            short8v afrag = __builtin_bit_cast(short8v, abase[cc * 64]);
            int k2 = c * 64 + h * 16;
            int byte = (pl << 11) + ((k2 ^ (((k2 >> 7) & 7) << 4)) ^ nswr);
            short8v bfrag = *(const short8v*)((const char*)zP + byte);
            dacc = __builtin_amdgcn_mfma_f32_16x16x32_bf16(afrag, bfrag, dacc, 0, 0, 0);
        }

        // ---- (E) LN9(t+1) from prefetched regs -> zcs[buf^1] ----
        if (tid < 256 && t < 7)
            ln9_store(buf ^ 1, tt0n + qn, pxn, qn, xnx);

        __syncthreads();   // (F) zP free for next conv; zcs[buf^1] ready
    }

    // ---- epilogue: cross-wave reduce (dred aliased into zP) + fc2 + tanh ----
    float* dred = (float*)zP;                     // [8][16][16] floats = 8KB
    *(f32x4*)&dred[(wv * 16 + pl) * 16 + h * 4] = dacc;
    __syncthreads();
    if (tid < 256) {
        int n4 = tid >> 4, j = tid & 15;
        float hj = 0.f;
#pragma unroll
        for (int w = 0; w < 8; ++w) hj += dred[(w * 16 + n4) * 16 + j];
        hj = fmaxf(hj + fc1b[j], 0.f);
        float th[5];
#pragma unroll
        for (int d = 0; d < 5; ++d) {
            float sd = hj * fc2w[j * 5 + d];
            sd += __shfl_xor(sd, 1, 64); sd += __shfl_xor(sd, 2, 64);
            sd += __shfl_xor(sd, 4, 64); sd += __shfl_xor(sd, 8, 64);
            th[d] = sd;
        }
        if (j < 5) outtheta[(base16 + n4) * TD + j] = tanhf(th[j] + fc2b[j]);
    }
}

// ---------------------------------------------------------------------------
extern "C" void kernel_launch(void* const* d_in, const int* in_sizes, int n_in,
                              void* d_out, int out_size, void* d_ws, size_t ws_size,
                              hipStream_t stream) {
    const float* x     = (const float*)d_in[0];
    const float* thraw = (const float*)d_in[1];
    const float* lniw  = (const float*)d_in[2];
    const float* lnib  = (const float*)d_in[3];
    const float* w1c   = (const float*)d_in[4];
    const float* b1c   = (const float*)d_in[5];
    const float* w2c   = (const float*)d_in[6];
    const float* b2c   = (const float*)d_in[7];
    const float* lncw  = (const float*)d_in[8];
    const float* lncb  = (const float*)d_in[9];
    const float* fc1w  = (const float*)d_in[10];
    const float* fc1b  = (const float*)d_in[11];
    const float* fc2w  = (const float*)d_in[12];
    const float* fc2b  = (const float*)d_in[13];
    float* out  = (float*)d_out;
    float* ws   = (float*)d_ws;
    float* Bf   = ws + WS_BF;
    int4v* wimg = (int4v*)(ws + WS_WIMG);
    int4v* aimg = (int4v*)(ws + WS_AIMG);
    float* xp   = ws + WS_XPIX;
    int use_xp  = (ws_size >= (size_t)(WS_XPIX + NP * CCH * TT) * 4) ? 1 : 0;
    int npre    = use_xp ? (65 + 512) : 65;

    hipLaunchKernelGGL(k_pre, dim3(npre), dim3(256), 0, stream,
                       lniw, lnib, w1c, b1c, w2c, fc1w, x, Bf, wimg, aimg, xp, use_xp);
    hipLaunchKernelGGL(k_cpab, dim3((NP * 13) / 256), dim3(256), 0, stream,
                       x, xp, use_xp, thraw, Bf, 0.5f, out + OUT1, out + OUT3, 1);
    hipLaunchKernelGGL(k_loc, dim3(NP / 16), dim3(512), 0, stream,
                       x, out + OUT1, wimg, aimg, b2c, lncw, lncb,
                       fc1b, fc2w, fc2b, out + OUT2);
    hipLaunchKernelGGL(k_cpab, dim3((NP * 13) / 256), dim3(256), 0, stream,
                       x, xp, use_xp, out + OUT2, Bf, 1.0f, out + OUT0, out, 0);
}

// Round 18
// 160.359 us; speedup vs baseline: 3.8502x; 1.1478x over previous
//
#include <hip/hip_runtime.h>
#include <math.h>

// Problem constants
#define TT   52        // time steps
#define BBAT 4         // batch
#define CCH  9         // input channels
#define HWP  4096      // 64*64 pixels per image
#define FF   64        // features
#define NP   16384     // b*h*w pixels
#define TD   5         // theta dim
#define NCC  6         // tessellation cells
#define TSTRIDE 147456 // b*c*h*w (stride of t in x, floats)

// output offsets (floats)
#define OUT0 0
#define OUT1 (NP*CCH*TT)        // x_shift_pix
#define OUT2 (2*NP*CCH*TT)      // theta_pred
#define OUT3 (OUT2 + NP*TD)     // theta_shift

// workspace offsets (floats)
#define WS_BF    0      // 60 floats: CPAB basis
#define WS_WIMG  1024   // 12*64 int4: w1a/w2a fragment image
#define WS_AIMG  4096   // 8*32*64 int4 = 65536 floats: fc1w A-fragment image
#define WS_XPIX  69632  // NP*CCH*TT floats: x pixel-major [n][c][t] (optional)

typedef __attribute__((ext_vector_type(8)))  short short8v;
typedef __attribute__((ext_vector_type(4)))  float f32x4;
typedef __attribute__((ext_vector_type(4)))  int   int4v;
typedef __attribute__((ext_vector_type(2)))  int   int2v;

// RNE f32->bf16 bits, packed pair (scalar fallback, prep kernels)
__device__ __forceinline__ unsigned bfb(float f) {
    unsigned x = __builtin_bit_cast(unsigned, f);
    return (x + 0x7fffu + ((x >> 16) & 1u)) >> 16;
}
__device__ __forceinline__ unsigned pk2(float a, float b) {
    return bfb(a) | (bfb(b) << 16);
}
// HW packed convert (1 VALU op): D.lo = bf16(a), D.hi = bf16(b)
__device__ __forceinline__ unsigned cvtpk(float a, float b) {
    unsigned r;
    asm("v_cvt_pk_bf16_f32 %0, %1, %2" : "=v"(r) : "v"(a), "v"(b));
    return r;
}
// zP row-XOR helper
__device__ __forceinline__ int nswz(int n) {
    return (((n ^ (n >> 3)) & 1) << 6) | (((n >> 1) & 3) << 4);
}

// ---------------------------------------------------------------------------
// k_pre: merged prep. block 0: basis (wave 0) + conv fragments (wave 1);
// blocks 1..64: fc1w A-fragment image; blocks 65..576: x -> xp transpose
// (32-pixel tiles, all 9 channels staged in LDS [468][33], coalesced writes).
// ---------------------------------------------------------------------------
__global__ __launch_bounds__(256) void k_pre(
    const float* __restrict__ lniw, const float* __restrict__ lnib,
    const float* __restrict__ w1c,  const float* __restrict__ b1c,
    const float* __restrict__ w2c,  const float* __restrict__ fc1w,
    const float* __restrict__ x,
    float* __restrict__ Bout, int4v* __restrict__ wimg,
    int4v* __restrict__ aimg, float* __restrict__ xp, int use_xp)
{
    __shared__ float ld[468 * 33];   // 61.8KB (transpose blocks only)
    int blk = blockIdx.x;
    int tid = threadIdx.x;

    if (blk == 0) {
        if (tid < 64) {
            // ---- basis: np.linalg.svd(L) null-space (dgesdd LQ path) ----
            int k = tid;
            double Acol[7], Vcol[7], Mcol[5];
#pragma unroll
            for (int r = 0; r < 7; r++) { Acol[r] = 0.0; Vcol[r] = 0.0; }
#pragma unroll
            for (int j = 0; j < 5; j++) Mcol[j] = 0.0;
            if (k < 12) {
#pragma unroll
                for (int j = 1; j < 6; j++) {
                    int r = j - 1;
                    double xj = (double)j / 6.0;
                    if (k == 2 * (j - 1))     Acol[r] = xj;
                    if (k == 2 * (j - 1) + 1) Acol[r] = 1.0;
                    if (k == 2 * j)           Acol[r] = -xj;
                    if (k == 2 * j + 1)       Acol[r] = -1.0;
                }
                if (k == 1)  Acol[5] = 1.0;
                if (k == 10) Acol[6] = 1.0;
                if (k == 11) Acol[6] = 1.0;
#pragma unroll
                for (int j = 0; j < 5; j++) Mcol[j] = (k == 7 + j) ? 1.0 : 0.0;
            }
            double tau[7];
#pragma unroll
            for (int i = 0; i < 7; i++) {
                double c = (k > i && k < 12) ? Acol[i] * Acol[i] : 0.0;
#pragma unroll
                for (int off = 1; off < 64; off <<= 1) c += __shfl_xor(c, off, 64);
                double alpha = __shfl(Acol[i], i, 64);
                double t_i, vk;
                if (c == 0.0) {
                    t_i = 0.0;
                    vk = (k == i) ? 1.0 : 0.0;
                } else {
                    double nrm  = sqrt(alpha * alpha + c);
                    double beta = (alpha >= 0.0) ? -nrm : nrm;  // Fortran SIGN
                    t_i = (beta - alpha) / beta;
                    double inv = 1.0 / (alpha - beta);
                    vk = (k == i) ? 1.0 : ((k > i && k < 12) ? Acol[i] * inv : 0.0);
                }
                tau[i]  = t_i;
                Vcol[i] = vk;
#pragma unroll
                for (int r = 0; r < 7; r++) {
                    if (r > i) {
                        double w = Acol[r] * vk;
#pragma unroll
                        for (int off = 1; off < 64; off <<= 1) w += __shfl_xor(w, off, 64);
                        Acol[r] -= t_i * w * vk;
                    }
                }
            }
#pragma unroll
            for (int i = 6; i >= 0; i--) {
#pragma unroll
                for (int j = 0; j < 5; j++) {
                    double w = Mcol[j] * Vcol[i];
#pragma unroll
                    for (int off = 1; off < 64; off <<= 1) w += __shfl_xor(w, off, 64);
                    Mcol[j] -= tau[i] * w * Vcol[i];
                }
            }
            if (k < 12) {
#pragma unroll
                for (int j = 0; j < 5; j++) Bout[k * 5 + j] = (float)Mcol[j];
            }
        } else if (tid < 128) {
            // ---- conv1/conv2 MFMA A-fragments -> wimg ----
            int lane = tid - 64;
            int pl = lane & 15, h = lane >> 4;
#pragma unroll
            for (int mt = 0; mt < 4; ++mt) {
                int f = mt * 16 + pl;
                float b0f = b1c[f];
#pragma unroll
                for (int c = 0; c < 9; ++c) b0f += lnib[c] * w1c[c * 64 + f];
                float v[8];
#pragma unroll
                for (int i = 0; i < 8; ++i) {
                    int c  = h * 8 + i;
                    int cc = c < 9 ? c : 8;
                    float lv = lniw[cc] * w1c[cc * 64 + f];
                    v[i] = (c < 9) ? lv : ((c == 9) ? b0f : 0.f);
                }
                wimg[mt * 64 + lane] = (int4v){(int)pk2(v[0],v[1]), (int)pk2(v[2],v[3]),
                                               (int)pk2(v[4],v[5]), (int)pk2(v[6],v[7])};
            }
#pragma unroll
            for (int mt2 = 0; mt2 < 4; ++mt2) {
                int g = mt2 * 16 + pl;
#pragma unroll
                for (int ks = 0; ks < 2; ++ks) {
                    float v[8];
#pragma unroll
                    for (int i = 0; i < 8; ++i) v[i] = w2c[(ks * 32 + h * 8 + i) * 64 + g];
                    wimg[(4 + mt2 * 2 + ks) * 64 + lane] =
                        (int4v){(int)pk2(v[0],v[1]), (int)pk2(v[2],v[3]),
                                (int)pk2(v[4],v[5]), (int)pk2(v[6],v[7])};
                }
            }
        }
    } else if (blk <= 64) {
        // ---- fc1w -> bf16 A-fragment image (pad positions zeroed) ----
        int gid  = (blk - 1) * 256 + tid;
        int lane = gid & 63;
        int tc   = gid >> 6;
        int t = tc >> 5, c = tc & 31;
        int bt = t >> 2, tt0 = (t & 3) << 4;
        int m = lane & 15, h = lane >> 4;
        float v[8];
#pragma unroll
        for (int i = 0; i < 8; ++i) {
            int k = c * 32 + h * 8 + i;
            int pos_l = k >> 6, g = k & 63;
            int tt = tt0 + pos_l;
            v[i] = (tt < 52) ? fc1w[(bt * 3328 + g * 52 + tt) * 16 + m] : 0.f;
        }
        aimg[gid] = (int4v){(int)pk2(v[0],v[1]), (int)pk2(v[2],v[3]),
                            (int)pk2(v[4],v[5]), (int)pk2(v[6],v[7])};
    } else if (use_xp) {
        // ---- transpose: 32-pixel tiles, all 9 channels, coalesced writes ----
        int b2 = blk - 65;               // 0..511
        int b  = b2 >> 7, pt = b2 & 127;
        int p0 = pt * 32;
        for (int idx = tid; idx < 9 * 52 * 32; idx += 256) {
            int c  = idx / 1664;         // 52*32
            int r  = idx - c * 1664;
            int t  = r >> 5, pp = r & 31;
            ld[(c * 52 + t) * 33 + pp] = x[((t * BBAT + b) * CCH + c) * HWP + p0 + pp];
        }
        __syncthreads();
        int wv_ = tid >> 6, ln = tid & 63;
        for (int pn = wv_; pn < 32; pn += 4) {
            float* dst = xp + (size_t)(b * HWP + p0 + pn) * 468;
#pragma unroll
            for (int e0 = 0; e0 < 468; e0 += 64) {
                int e = e0 + ln;
                if (e < 468) dst[e] = ld[e * 33 + pn];
            }
        }
    }
}

// ---------------------------------------------------------------------------
// k_cpab: ODE + lerp, 4 chains/thread. Round-18 delta: chain mapping
// tt = 4*i0 + c (4 CONSECUTIVE tt per thread) so the 36 scattered b32
// output stores become 9 float4 stores (runs of 13 lanes cover 52
// contiguous floats per (n,ch)); fixes the ~40% write overfetch seen in
// r16 counters (44.6MB vs 31MB ideal). ODE form unchanged from r17
// (uniform 100-step loop, float2 LDS table, 1 ds_read_b64/step).
// ---------------------------------------------------------------------------
__global__ __launch_bounds__(256) void k_cpab(
    const float* __restrict__ x, const float* __restrict__ xp, int use_xp,
    const float* __restrict__ theta, const float* __restrict__ Bf,
    float scale, float* __restrict__ out,
    float* __restrict__ outts, int do_ts)
{
    __shared__ float2 ABs[256 * 13];   // 26.6KB: {A, B} per (thread, cell)
    int tid = threadIdx.x;
    int gid = blockIdx.x * 256 + tid;
    if (gid >= NP * 13) return;
    if (do_ts && gid < NP * TD) outts[gid] = 0.5f * theta[gid];
    int n  = gid / 13;
    int i0 = gid - n * 13;

    float th[TD];
#pragma unroll
    for (int j = 0; j < TD; j++) th[j] = scale * theta[n * TD + j];

#pragma unroll
    for (int i = 0; i < NCC; i++) {
        float aa = 0.f, bb = 0.f;
#pragma unroll
        for (int j = 0; j < TD; j++) {
            aa += th[j] * Bf[(2 * i) * TD + j];
            bb += th[j] * Bf[(2 * i + 1) * TD + j];
        }
        ABs[tid * 13 + i] = make_float2(fmaf(0.01f, aa, 1.0f), 0.01f * bb);
    }
    const float2* ABp = &ABs[tid * 13];

    float xcs[4];
#pragma unroll
    for (int c = 0; c < 4; ++c) xcs[c] = (float)(i0 * 4 + c) / 51.0f;

    for (int s = 0; s < 100; ++s) {
#pragma unroll
        for (int c = 0; c < 4; ++c) {
            int i = (int)(xcs[c] * 6.0f);
            i = i < 5 ? i : 5;
            float2 ab = ABp[i];
            xcs[c] = __builtin_amdgcn_fmed3f(fmaf(ab.x, xcs[c], ab.y), 0.0f, 1.0f);
        }
    }

    // interpolation weights per chain
    int   x0v[4];
    float wv4[4];
#pragma unroll
    for (int c = 0; c < 4; ++c) {
        float pos = xcs[c] * 51.0f;
        int x0 = (int)floorf(pos);
        if (x0 < 0) x0 = 0;
        if (x0 > 50) x0 = 50;
        x0v[c] = x0;
        wv4[c] = pos - (float)x0;
    }

    if (use_xp) {
        const float* row = xp + (size_t)n * (CCH * TT);
        float* dst = out + n * (CCH * TT) + i0 * 4;
#pragma unroll
        for (int ch = 0; ch < CCH; ++ch) {
            f32x4 v;
#pragma unroll
            for (int c = 0; c < 4; ++c) {
                float d0 = row[ch * TT + x0v[c]];
                float d1 = row[ch * TT + x0v[c] + 1];
                v[c] = d0 * (1.0f - wv4[c]) + d1 * wv4[c];
            }
            *(f32x4*)(dst + ch * TT) = v;
        }
    } else {
        int bb_ = n >> 12, p = n & 4095;
        float* dst = out + n * (CCH * TT) + i0 * 4;
#pragma unroll
        for (int ch = 0; ch < CCH; ++ch) {
            f32x4 v;
#pragma unroll
            for (int c = 0; c < 4; ++c) {
                int base0 = ((x0v[c] * BBAT + bb_) * CCH) * HWP + p;
                float d0 = x[base0 + ch * HWP];
                float d1 = x[base0 + ch * HWP + TSTRIDE];
                v[c] = d0 * (1.0f - wv4[c]) + d1 * wv4[c];
            }
            *(f32x4*)(dst + ch * TT) = v;
        }
    }
}

// ---------------------------------------------------------------------------
// k_loc (full-MFMA, 16 px / 8 waves / 512 threads). Structure unchanged from
// round 13. Round-18 delta: T5 s_setprio(1/0) around the fc1 MFMA cluster
// (phase-split schedule -> scheduler can favor MFMA-entering waves).
// ---------------------------------------------------------------------------
__global__ __launch_bounds__(512, 2) void k_loc(
    const float* __restrict__ x,     // [52,4,9,64,64]
    const float* __restrict__ xs,    // x_shift_pix [N,9,52]
    const int4v* __restrict__ wimg,  // conv fragment image
    const int4v* __restrict__ aimg,  // fc1w A-fragment image
    const float* __restrict__ b2c,
    const float* __restrict__ lncw,  const float* __restrict__ lncb,
    const float* __restrict__ fc1b,
    const float* __restrict__ fc2w,  const float* __restrict__ fc2b,
    float* __restrict__ outtheta)    // [N,5]
{
    __shared__ int4v          zcs[2][256];     // 8KB  zc lo-8, double-buffered
    __shared__ unsigned       zchs[2][256];    // 2KB  pk2(c8, bias), dbuf
    __shared__ unsigned short y1b[8][16][64];  // 16KB per-wave y1 tile
    __shared__ unsigned short zP[16][1024];    // 32KB z2 [px][k]; epilogue: dred alias

    int tid    = threadIdx.x;
    int lane   = tid & 63;
    int wv     = tid >> 6;          // 0..7
    int base16 = blockIdx.x * 16;
    int bb_    = base16 >> 12, p0 = base16 & 4095;
    int pl     = lane & 15;
    int h      = lane >> 4;

    auto ln9_load = [&](int bt_, int tt_, int px_, float* dst) {
        if (tt_ < 52) {
            if (bt_ == 0) {
                int base = ((tt_ * BBAT + bb_) * CCH) * HWP + p0 + px_;
#pragma unroll
                for (int c = 0; c < 9; ++c) dst[c] = x[base + c * HWP];
            } else {
                int base = (base16 + px_) * (CCH * TT) + tt_;
#pragma unroll
                for (int c = 0; c < 9; ++c) dst[c] = xs[base + c * TT];
            }
        }
    };
    auto ln9_store = [&](int buf_, int tt_, int px_, int q_, const float* xin_) {
        float zc[9], bias;
        if (tt_ < 52) {
            float s1 = 0.f, s2 = 0.f;
#pragma unroll
            for (int c = 0; c < 9; ++c) { s1 += xin_[c]; s2 += xin_[c] * xin_[c]; }
            float m  = s1 * (1.0f / 9.0f);
            float vv = fmaxf(s2 * (1.0f / 9.0f) - m * m, 0.f);
            float rs = rsqrtf(vv + 1e-5f);
#pragma unroll
            for (int c = 0; c < 9; ++c) zc[c] = (xin_[c] - m) * rs;
            bias = 1.0f;
        } else {
#pragma unroll
            for (int c = 0; c < 9; ++c) zc[c] = 0.f;
            bias = 0.f;
        }
        zcs[buf_][px_ * 16 + (q_ ^ (px_ & 7))] =
            (int4v){(int)cvtpk(zc[0], zc[1]), (int)cvtpk(zc[2], zc[3]),
                    (int)cvtpk(zc[4], zc[5]), (int)cvtpk(zc[6], zc[7])};
        zchs[buf_][px_ * 16 + q_] = cvtpk(zc[8], bias);
    };

    // ---- fragments (coalesced b128 from wimg) ----
    short8v w1a[4], w2a[4][2];
#pragma unroll
    for (int mt = 0; mt < 4; ++mt)
        w1a[mt] = __builtin_bit_cast(short8v, wimg[mt * 64 + lane]);
#pragma unroll
    for (int mt2 = 0; mt2 < 4; ++mt2)
#pragma unroll
        for (int ks = 0; ks < 2; ++ks)
            w2a[mt2][ks] = __builtin_bit_cast(short8v, wimg[(4 + mt2 * 2 + ks) * 64 + lane]);

    f32x4 b2v[4], lw4[4], lb4[4];
#pragma unroll
    for (int mt2 = 0; mt2 < 4; ++mt2) {
        b2v[mt2] = *(const f32x4*)(b2c  + mt2 * 16 + h * 4);
        lw4[mt2] = *(const f32x4*)(lncw + mt2 * 16 + h * 4);
        lb4[mt2] = *(const f32x4*)(lncb + mt2 * 16 + h * 4);
    }

    f32x4 dacc = (f32x4){0.f, 0.f, 0.f, 0.f};

    // ---- prologue: stage tile 0 (bt=0) ----
    if (tid < 256) {
        float xcur[9];
        int px = tid & 15, q = tid >> 4;
        ln9_load(0, q, px, xcur);
        ln9_store(0, q, px, q, xcur);
    }
    __syncthreads();

    for (int t = 0; t < 8; ++t) {
        int buf = t & 1;

        // ---- (A) prefetch tile t+1 into registers ----
        float xnx[9];
        int btn = (t + 1) >> 2, tt0n = ((t + 1) & 3) << 4;
        int pxn = 0, qn = 0;
        if (tid < 256 && t < 7) {
            if (btn == 0) { pxn = tid & 15; qn = tid >> 4; }
            else          { pxn = tid >> 4; qn = tid & 15; }
            ln9_load(btn, tt0n + qn, pxn, xnx);
        }

        // ---- (B) conv: 2 pixels per wave (reads zcs[buf]) ----
        int sw = (pl & 7) << 3;
#pragma unroll
        for (int sub = 0; sub < 2; ++sub) {
            int px = wv * 2 + sub;
            int nswp = nswz(px);

            short8v b1f;
            if (h == 1) {
                unsigned zv = zchs[buf][px * 16 + pl];
                b1f = __builtin_bit_cast(short8v, (int4v){(int)zv, 0, 0, 0});
            } else {
                b1f = __builtin_bit_cast(short8v, zcs[buf][px * 16 + (pl ^ (px & 7))]);
            }

#pragma unroll
            for (int mt = 0; mt < 4; ++mt) {
                f32x4 c1 = __builtin_amdgcn_mfma_f32_16x16x32_bf16(
                    w1a[mt], b1f, (f32x4){0.f, 0.f, 0.f, 0.f}, 0, 0, 0);
                float v0 = fmaxf(c1[0], 0.f), v1 = fmaxf(c1[1], 0.f);
                float v2 = fmaxf(c1[2], 0.f), v3 = fmaxf(c1[3], 0.f);
                int f0 = (mt * 16 + h * 4) ^ sw;
                *(int2v*)&y1b[wv][pl][f0] = (int2v){(int)cvtpk(v0, v1), (int)cvtpk(v2, v3)};
            }

            short8v b2f0 = *(const short8v*)&y1b[wv][pl][(h * 8) ^ sw];
            short8v b2f1 = *(const short8v*)&y1b[wv][pl][(32 + h * 8) ^ sw];
            float y2[4][4];
#pragma unroll
            for (int mt2 = 0; mt2 < 4; ++mt2) {
                f32x4 c2 = b2v[mt2];
                c2 = __builtin_amdgcn_mfma_f32_16x16x32_bf16(w2a[mt2][0], b2f0, c2, 0, 0, 0);
                c2 = __builtin_amdgcn_mfma_f32_16x16x32_bf16(w2a[mt2][1], b2f1, c2, 0, 0, 0);
                y2[mt2][0] = fmaxf(c2[0], 0.f);
                y2[mt2][1] = fmaxf(c2[1], 0.f);
                y2[mt2][2] = fmaxf(c2[2], 0.f);
                y2[mt2][3] = fmaxf(c2[3], 0.f);
            }

            // LN64
            float s = 0.f, q = 0.f;
#pragma unroll
            for (int mt2 = 0; mt2 < 4; ++mt2)
#pragma unroll
                for (int r = 0; r < 4; ++r) { s += y2[mt2][r]; q = fmaf(y2[mt2][r], y2[mt2][r], q); }
            s += __shfl_xor(s, 16, 64); s += __shfl_xor(s, 32, 64);
            q += __shfl_xor(q, 16, 64); q += __shfl_xor(q, 32, 64);
            float m2  = s * (1.0f / 64.0f);
            float v2_ = fmaxf(q * (1.0f / 64.0f) - m2 * m2, 0.f);
            float rs2 = rsqrtf(v2_ + 1e-5f);

            // z2 (pad A-columns in aimg are zero; no mask needed)
#pragma unroll
            for (int mt2 = 0; mt2 < 4; ++mt2)
#pragma unroll
                for (int r = 0; r < 4; ++r)
                    y2[mt2][r] = fmaf((y2[mt2][r] - m2) * rs2, lw4[mt2][r], lb4[mt2][r]);

            // z2 pairs -> zP (swizzled)
#pragma unroll
            for (int mt2 = 0; mt2 < 4; ++mt2)
#pragma unroll
                for (int rp = 0; rp < 2; ++rp) {
                    int g0 = mt2 * 16 + h * 4 + rp * 2;
                    int k2 = pl * 128 + g0 * 2;
                    int byte = (px << 11) + ((k2 ^ (((k2 >> 7) & 7) << 4)) ^ nswp);
                    *(unsigned*)((char*)zP + byte) = cvtpk(y2[mt2][rp * 2], y2[mt2][rp * 2 + 1]);
                }
        }
        __syncthreads();   // (C) zP visible to fc1

        // ---- (D) fc1 MFMA: wave covers chunks wv*4..wv*4+3 (T5 setprio) ----
        const int4v* abase = aimg + (t * 32 + wv * 4) * 64 + lane;
        int nswr = nswz(pl);
        __builtin_amdgcn_s_setprio(1);
#pragma unroll
        for (int cc = 0; cc < 4; ++cc) {
            int c = wv * 4 + cc;
            short8v afrag = __builtin_bit_cast(short8v, abase[cc * 64]);
            int k2 = c * 64 + h * 16;
            int byte = (pl << 11) + ((k2 ^ (((k2 >> 7) & 7) << 4)) ^ nswr);
            short8v bfrag = *(const short8v*)((const char*)zP + byte);
            dacc = __builtin_amdgcn_mfma_f32_16x16x32_bf16(afrag, bfrag, dacc, 0, 0, 0);
        }
        __builtin_amdgcn_s_setprio(0);

        // ---- (E) LN9(t+1) from prefetched regs -> zcs[buf^1] ----
        if (tid < 256 && t < 7)
            ln9_store(buf ^ 1, tt0n + qn, pxn, qn, xnx);

        __syncthreads();   // (F) zP free for next conv; zcs[buf^1] ready
    }

    // ---- epilogue: cross-wave reduce (dred aliased into zP) + fc2 + tanh ----
    float* dred = (float*)zP;                     // [8][16][16] floats = 8KB
    *(f32x4*)&dred[(wv * 16 + pl) * 16 + h * 4] = dacc;
    __syncthreads();
    if (tid < 256) {
        int n4 = tid >> 4, j = tid & 15;
        float hj = 0.f;
#pragma unroll
        for (int w = 0; w < 8; ++w) hj += dred[(w * 16 + n4) * 16 + j];
        hj = fmaxf(hj + fc1b[j], 0.f);
        float th[5];
#pragma unroll
        for (int d = 0; d < 5; ++d) {
            float sd = hj * fc2w[j * 5 + d];
            sd += __shfl_xor(sd, 1, 64); sd += __shfl_xor(sd, 2, 64);
            sd += __shfl_xor(sd, 4, 64); sd += __shfl_xor(sd, 8, 64);
            th[d] = sd;
        }
        if (j < 5) outtheta[(base16 + n4) * TD + j] = tanhf(th[j] + fc2b[j]);
    }
}

// ---------------------------------------------------------------------------
extern "C" void kernel_launch(void* const* d_in, const int* in_sizes, int n_in,
                              void* d_out, int out_size, void* d_ws, size_t ws_size,
                              hipStream_t stream) {
    const float* x     = (const float*)d_in[0];
    const float* thraw = (const float*)d_in[1];
    const float* lniw  = (const float*)d_in[2];
    const float* lnib  = (const float*)d_in[3];
    const float* w1c   = (const float*)d_in[4];
    const float* b1c   = (const float*)d_in[5];
    const float* w2c   = (const float*)d_in[6];
    const float* b2c   = (const float*)d_in[7];
    const float* lncw  = (const float*)d_in[8];
    const float* lncb  = (const float*)d_in[9];
    const float* fc1w  = (const float*)d_in[10];
    const float* fc1b  = (const float*)d_in[11];
    const float* fc2w  = (const float*)d_in[12];
    const float* fc2b  = (const float*)d_in[13];
    float* out  = (float*)d_out;
    float* ws   = (float*)d_ws;
    float* Bf   = ws + WS_BF;
    int4v* wimg = (int4v*)(ws + WS_WIMG);
    int4v* aimg = (int4v*)(ws + WS_AIMG);
    float* xp   = ws + WS_XPIX;
    int use_xp  = (ws_size >= (size_t)(WS_XPIX + NP * CCH * TT) * 4) ? 1 : 0;
    int npre    = use_xp ? (65 + 512) : 65;

    hipLaunchKernelGGL(k_pre, dim3(npre), dim3(256), 0, stream,
                       lniw, lnib, w1c, b1c, w2c, fc1w, x, Bf, wimg, aimg, xp, use_xp);
    hipLaunchKernelGGL(k_cpab, dim3((NP * 13) / 256), dim3(256), 0, stream,
                       x, xp, use_xp, thraw, Bf, 0.5f, out + OUT1, out + OUT3, 1);
    hipLaunchKernelGGL(k_loc, dim3(NP / 16), dim3(512), 0, stream,
                       x, out + OUT1, wimg, aimg, b2c, lncw, lncb,
                       fc1b, fc2w, fc2b, out + OUT2);
    hipLaunchKernelGGL(k_cpab, dim3((NP * 13) / 256), dim3(256), 0, stream,
                       x, xp, use_xp, out + OUT2, Bf, 1.0f, out + OUT0, out, 0);
}